// Round 11
// baseline (210.626 us; speedup 1.0000x reference)
//
#include <hip/hip_runtime.h>

// BatchWiseTripletLoss: n=8192, d=128, 512 classes, scalar output.
// Round-11: class-sorted rows (round 7) + LDS-staged B with a panel loop.
// Fragment-order ebB makes a block's B slice (8 stripes = 32 KB) contiguous,
// so global_load_lds stages it linearly (no swizzle; ds_read_b128 reads are
// lane-contiguous, conflict-free). One barrier per block, then a barrier-free
// sweep: 4 row-panels x 8 column stripes. B is shared by 4 waves via LDS
// (L2 traffic /4 vs round 10) and by 4 panels (amortized staging).
// launch_bounds(256,4): footprint ~80-100 unified regs (ping-pong B regs
// gone), so the 128-reg cap does NOT spill (unlike rounds 3/6 where the
// footprint genuinely exceeded 128). 4 blocks/CU x 32 KB = 128 KB LDS.

#define D 128
#define BM 128   // rows per panel = 4 waves x 32
#define ROWG 4   // panels per block
#define SPLIT 64 // column slices
#define NPART SPLIT
#define NCLS 512
#define MARGIN 0.1f
#define NEG_FLOOR 0.6f
#define NINF -1e30f

typedef short bf16x8 __attribute__((ext_vector_type(8)));
typedef float f32x4 __attribute__((ext_vector_type(4)));

__device__ __forceinline__ unsigned short f2bf(float f) {
  unsigned u = __float_as_uint(f);
  u += 0x7FFFu + ((u >> 16) & 1u);
  return (unsigned short)(u >> 16);
}

// ---- S1: per-chunk class histogram (64 chunks x 128 rows) ----
__global__ void k_hist(const int* __restrict__ tgt, int* __restrict__ H) {
  __shared__ int h[NCLS];
  for (int i = threadIdx.x; i < NCLS; i += 128) h[i] = 0;
  __syncthreads();
  atomicAdd(&h[tgt[blockIdx.x * 128 + threadIdx.x]], 1);
  __syncthreads();
  for (int i = threadIdx.x; i < NCLS; i += 128)
    H[blockIdx.x * NCLS + i] = h[i];
}

// ---- S2: one-block scan -> per-chunk per-class scatter bases ----
__global__ void k_scan(const int* __restrict__ H, int* __restrict__ CB) {
  __shared__ int wsum[8];
  const int c = threadIdx.x;  // class, 512 threads
  int t = 0;
#pragma unroll 8
  for (int k = 0; k < 64; ++k) t += H[k * NCLS + c];
  const int lane = c & 63, w = c >> 6;
  int v = t;
#pragma unroll
  for (int off = 1; off < 64; off <<= 1) {
    int u = __shfl_up(v, off, 64);
    if (lane >= off) v += u;
  }
  if (lane == 63) wsum[w] = v;
  __syncthreads();
  if (c < 8) {
    int x = wsum[c];
#pragma unroll
    for (int off = 1; off < 8; off <<= 1) {
      int u = __shfl_up(x, off, 64);
      if (lane >= off) x += u;
    }
    wsum[c] = x;
  }
  __syncthreads();
  int base = v + ((w > 0) ? wsum[w - 1] : 0) - t;  // exclusive prefix
  int run = base;
#pragma unroll 8
  for (int k = 0; k < 64; ++k) {
    CB[k * NCLS + c] = run;
    run += H[k * NCLS + c];
  }
}

// ---- S3: stable scatter (thread = class, block = chunk) ----
__global__ void k_scatter(const int* __restrict__ tgt,
                          const int* __restrict__ CB, int* __restrict__ perm) {
  const int c = threadIdx.x;  // 512 threads
  int pos = CB[blockIdx.x * NCLS + c];
  const int base = blockIdx.x * 128;
  for (int j = 0; j < 128; ++j) {
    int cls = tgt[base + j];
    if (cls == c) perm[pos++] = base + j;
  }
}

// ---- K1: gather-normalize rows into fragment-order bf16 ----
// ebB chunk (16B) at [(stripe*4+ks)*64+lane] holds sorted row
// stripe*16+(lane&15), elements [(ks*4+(lane>>4))*8 .. +8).
__global__ void k_normB(const float* __restrict__ emb,
                        const int* __restrict__ tgt,
                        const int* __restrict__ perm, uint4* __restrict__ ebB,
                        int* __restrict__ tgtS, int n) {
  const int s = blockIdx.x;         // 16-row (sorted) stripe
  const int rl = threadIdx.x >> 4;  // row within stripe
  const int c = threadIdx.x & 15;   // 16B chunk within row
  const int p = s * 16 + rl;        // sorted row
  const int orig = perm[p];
  const float* q = emb + (size_t)orig * D + c * 8;
  float4 v0 = *(const float4*)q;
  float4 v1 = *(const float4*)(q + 4);
  float ss = v0.x * v0.x + v0.y * v0.y + v0.z * v0.z + v0.w * v0.w +
             v1.x * v1.x + v1.y * v1.y + v1.z * v1.z + v1.w * v1.w;
#pragma unroll
  for (int off = 1; off < 16; off <<= 1) ss += __shfl_xor(ss, off, 64);
  float inv = 1.0f / fmaxf(sqrtf(ss), 1e-12f);
  uint4 wv;
  wv.x = (unsigned)f2bf(v0.x * inv) | ((unsigned)f2bf(v0.y * inv) << 16);
  wv.y = (unsigned)f2bf(v0.z * inv) | ((unsigned)f2bf(v0.w * inv) << 16);
  wv.z = (unsigned)f2bf(v1.x * inv) | ((unsigned)f2bf(v1.y * inv) << 16);
  wv.w = (unsigned)f2bf(v1.z * inv) | ((unsigned)f2bf(v1.w * inv) << 16);
  const int ks = c >> 2, g = c & 3;
  ebB[((s * 4 + ks) * 64) + (g * 16 + rl)] = wv;
  if (c == 0) tgtS[p] = tgt[orig];
}

// ---- K2/K4: LDS-B panel-loop GEMM pass, sorted-class epilogue ----
template <int PASS>
__global__ __launch_bounds__(256, 4) void k_pass5(
    const bf16x8* __restrict__ ebB, const int* __restrict__ tgtS,
    float* __restrict__ mneg_p, float* __restrict__ mpos_p,
    const float* __restrict__ thrNv, const float* __restrict__ thrPv,
    float* __restrict__ loss_p, int n) {
  __shared__ char Bs[32768];  // 8 column stripes x 4 KB, fragment order

  const int lane = threadIdx.x & 63;
  const int w = threadIdx.x >> 6;
  const int l15 = lane & 15, g = lane >> 4;

  const int nStr = (n / SPLIT) / 16;  // 8 stripes per block
  const int cs0 = blockIdx.y * nStr;
  const int pidx = blockIdx.y;
  const int m0 = blockIdx.x * (BM * ROWG);

  // Stage this block's B slice: contiguous 32 KB, linear copy.
  {
    const char* src = (const char*)ebB + (size_t)cs0 * 4096;
#pragma unroll
    for (int i = 0; i < 8; ++i) {
      __builtin_amdgcn_global_load_lds(
          (const __attribute__((address_space(1))) void*)(src + i * 4096 +
                                                          threadIdx.x * 16),
          (__attribute__((address_space(3))) void*)(Bs + i * 4096 +
                                                    threadIdx.x * 16),
          16, 0, 0);
    }
  }
  // Stripe class ranges (wave-uniform scalars).
  int slo[8], shi[8];
#pragma unroll
  for (int si = 0; si < 8; ++si) {
    slo[si] = tgtS[(cs0 + si) * 16];
    shi[si] = tgtS[(cs0 + si) * 16 + 15];
  }
  __syncthreads();  // B resident; no barriers after this point.

#pragma unroll 1
  for (int p = 0; p < ROWG; ++p) {
    const int rbase = m0 + p * BM + w * 32;  // wave's 32-row panel
    const int sA = rbase >> 4;
    const int clo = tgtS[rbase], chi = tgtS[rbase + 31];

    bf16x8 a[2][4];
#pragma unroll
    for (int mt = 0; mt < 2; ++mt)
#pragma unroll
      for (int ks = 0; ks < 4; ++ks)
        a[mt][ks] = ebB[((sA + mt) * 4 + ks) * 64 + lane];

    int tr[2][4];
#pragma unroll
    for (int mt = 0; mt < 2; ++mt) {
      int4 t4 = *(const int4*)(tgtS + rbase + mt * 16 + g * 4);
      tr[mt][0] = t4.x; tr[mt][1] = t4.y; tr[mt][2] = t4.z; tr[mt][3] = t4.w;
    }

    float accN[2][4], accP[2][4], lossA[2][4];
    float thrPmin = 0.f;
#pragma unroll
    for (int mt = 0; mt < 2; ++mt) {
      if (PASS == 0) {
#pragma unroll
        for (int r = 0; r < 4; ++r) {
          accN[mt][r] = NINF;
          accP[mt][r] = NINF;
        }
      } else {
        f32x4 vN = *(const f32x4*)(thrNv + rbase + mt * 16 + g * 4);
        f32x4 vP = *(const f32x4*)(thrPv + rbase + mt * 16 + g * 4);
#pragma unroll
        for (int r = 0; r < 4; ++r) {
          accN[mt][r] = vN[r];
          accP[mt][r] = vP[r];
          lossA[mt][r] = 0.0f;
        }
      }
    }
    if (PASS == 1) {  // wave-min of thr_neg (>= 0.5 via the 0.6 floor)
      float m = accP[0][0];
#pragma unroll
      for (int mt = 0; mt < 2; ++mt)
#pragma unroll
        for (int r = 0; r < 4; ++r) m = fminf(m, accP[mt][r]);
#pragma unroll
      for (int off = 1; off < 64; off <<= 1)
        m = fminf(m, __shfl_xor(m, off, 64));
      thrPmin = m;
    }

#pragma unroll
    for (int si = 0; si < 8; ++si) {
      bf16x8 b[4];
#pragma unroll
      for (int ks = 0; ks < 4; ++ks)
        b[ks] = *(const bf16x8*)(Bs + si * 4096 + ks * 1024 + lane * 16);
      const int cs = cs0 + si;
      const bool dirty = (clo <= shi[si]) && (slo[si] <= chi);

      f32x4 acc[2];
#pragma unroll
      for (int mt = 0; mt < 2; ++mt) acc[mt] = (f32x4){0.f, 0.f, 0.f, 0.f};
#pragma unroll
      for (int ks = 0; ks < 4; ++ks)
#pragma unroll
        for (int mt = 0; mt < 2; ++mt)
          acc[mt] = __builtin_amdgcn_mfma_f32_16x16x32_bf16(a[mt][ks], b[ks],
                                                            acc[mt], 0, 0, 0);
      if (!dirty) {  // pure negatives
        if (PASS == 0) {
#pragma unroll
          for (int mt = 0; mt < 2; ++mt)
#pragma unroll
            for (int r = 0; r < 4; ++r)
              accN[mt][r] = fmaxf(accN[mt][r], acc[mt][r]);
        } else {
#pragma unroll
          for (int mt = 0; mt < 2; ++mt) {
            float mx = fmaxf(fmaxf(acc[mt][0], acc[mt][1]),
                             fmaxf(acc[mt][2], acc[mt][3]));
            if (__any(mx > thrPmin)) {  // rare
#pragma unroll
              for (int r = 0; r < 4; ++r) {
                float s = acc[mt][r];
                lossA[mt][r] += (s > accP[mt][r]) ? s : 0.f;
              }
            }
          }
        }
      } else {  // class-range overlap: full verified path
        const int tc = tgtS[cs * 16 + l15];
#pragma unroll
        for (int mt = 0; mt < 2; ++mt) {
          const bool diagT = (rbase + mt * 16 == cs * 16);
#pragma unroll
          for (int r = 0; r < 4; ++r) {
            float s = acc[mt][r];
            bool same = (tr[mt][r] == tc);
            bool posOk = same && !(diagT && ((g * 4 + r) == l15));
            if (PASS == 0) {
              accN[mt][r] = fmaxf(accN[mt][r], same ? NINF : s);
              accP[mt][r] = fmaxf(accP[mt][r], posOk ? s : NINF);
            } else {
              bool cpos = posOk && (s < accN[mt][r]);
              bool cneg = !same && (s > accP[mt][r]);
              lossA[mt][r] += cpos ? (1.0f - s) : (cneg ? s : 0.f);
            }
          }
        }
      }
    }

    // Per-panel reduce over the 16 l15-lanes; lane l15==0 writes partials.
#pragma unroll
    for (int mt = 0; mt < 2; ++mt) {
#pragma unroll
      for (int r = 0; r < 4; ++r) {
        int row = rbase + mt * 16 + g * 4 + r;
        if (PASS == 0) {
          float vn = accN[mt][r], vp = accP[mt][r];
#pragma unroll
          for (int off = 1; off < 16; off <<= 1) {
            vn = fmaxf(vn, __shfl_xor(vn, off, 64));
            vp = fmaxf(vp, __shfl_xor(vp, off, 64));
          }
          if (l15 == 0) {
            mneg_p[(size_t)pidx * n + row] = vn;
            mpos_p[(size_t)pidx * n + row] = vp;
          }
        } else {
          float vl = lossA[mt][r];
#pragma unroll
          for (int off = 1; off < 16; off <<= 1)
            vl += __shfl_xor(vl, off, 64);
          if (l15 == 0) loss_p[(size_t)pidx * n + row] = vl;
        }
      }
    }
  }
}

// ---- K3: combine partial maxima -> per-row thresholds + has_pos ----
__global__ void k_combine(const float* __restrict__ mneg_p,
                          const float* __restrict__ mpos_p,
                          float* __restrict__ thrNv, float* __restrict__ thrPv,
                          float* __restrict__ hasp, int n) {
  int i = blockIdx.x * blockDim.x + threadIdx.x;
  if (i >= n) return;
  float vn = NINF, vp = NINF;
#pragma unroll
  for (int s = 0; s < NPART; ++s) {
    vn = fmaxf(vn, mneg_p[(size_t)s * n + i]);
    vp = fmaxf(vp, mpos_p[(size_t)s * n + i]);
  }
  thrNv[i] = vn + MARGIN;                    // thr_pos
  thrPv[i] = fmaxf(NEG_FLOOR, vp) - MARGIN;  // thr_neg (>= 0.5)
  hasp[i] = (vp > -1e29f) ? 1.f : 0.f;
}

// ---- K5a/K5b: deterministic final reduction ----
__global__ void k_final1(const float* __restrict__ loss_p,
                         const float* __restrict__ hasp,
                         float* __restrict__ bpart, int n) {
  __shared__ float red[256];
  int i = blockIdx.x * 256 + threadIdx.x;
  float acc = 0.f;
#pragma unroll
  for (int sp = 0; sp < NPART; ++sp) acc += loss_p[(size_t)sp * n + i];
  acc *= hasp[i];
  red[threadIdx.x] = acc;
  __syncthreads();
  for (int off = 128; off > 0; off >>= 1) {
    if ((int)threadIdx.x < off) red[threadIdx.x] += red[threadIdx.x + off];
    __syncthreads();
  }
  if (threadIdx.x == 0) bpart[blockIdx.x] = red[0];
}

__global__ void k_final2(const float* __restrict__ bpart,
                         float* __restrict__ out, int n, int nb) {
  int lane = threadIdx.x & 63;
  float v = (lane < nb) ? bpart[lane] : 0.f;
#pragma unroll
  for (int off = 1; off < 64; off <<= 1) v += __shfl_xor(v, off, 64);
  if (lane == 0) out[0] = v / (float)n;
}

extern "C" void kernel_launch(void* const* d_in, const int* in_sizes, int n_in,
                              void* d_out, int out_size, void* d_ws,
                              size_t ws_size, hipStream_t stream) {
  const float* emb = (const float*)d_in[0];
  const int* tgt = (const int*)d_in[1];
  float* out = (float*)d_out;
  const int n = in_sizes[1];  // 8192

  char* ws = (char*)d_ws;
  uint4* ebB = (uint4*)ws;  // fragment-ordered bf16, 2 MB
  size_t off = (size_t)n * D * sizeof(unsigned short);
  float* mneg_p = (float*)(ws + off);          // [NPART][n]
  float* mpos_p = mneg_p + (size_t)NPART * n;  // [NPART][n]
  float* loss_p = mpos_p + (size_t)NPART * n;  // [NPART][n]
  float* thrNv = loss_p + (size_t)NPART * n;   // [n]
  float* thrPv = thrNv + n;                    // [n]
  float* hasp = thrPv + n;                     // [n]
  float* bpart = hasp + n;                     // [32]
  int* H = (int*)(bpart + 64);                 // [64][512]
  int* CB = H + 64 * NCLS;                     // [64][512]
  int* perm = CB + 64 * NCLS;                  // [n]
  int* tgtS = perm + n;                        // [n]

  k_hist<<<n / 128, 128, 0, stream>>>(tgt, H);
  k_scan<<<1, NCLS, 0, stream>>>(H, CB);
  k_scatter<<<n / 128, NCLS, 0, stream>>>(tgt, CB, perm);
  k_normB<<<n / 16, 256, 0, stream>>>(emb, tgt, perm, ebB, tgtS, n);

  dim3 grid(n / (BM * ROWG), SPLIT);
  k_pass5<0><<<grid, 256, 0, stream>>>((const bf16x8*)ebB, tgtS, mneg_p,
                                       mpos_p, thrNv, thrPv, loss_p, n);
  k_combine<<<(n + 255) / 256, 256, 0, stream>>>(mneg_p, mpos_p, thrNv, thrPv,
                                                 hasp, n);
  k_pass5<1><<<grid, 256, 0, stream>>>((const bf16x8*)ebB, tgtS, mneg_p,
                                       mpos_p, thrNv, thrPv, loss_p, n);
  k_final1<<<n / 256, 256, 0, stream>>>(loss_p, hasp, bpart, n);
  k_final2<<<1, 64, 0, stream>>>(bpart, out, n, n / 256);
}

// Round 12
// 110.858 us; speedup vs baseline: 1.9000x; 1.9000x over previous
//
#include <hip/hip_runtime.h>

// BatchWiseTripletLoss: n=8192, d=128, 512 classes, scalar output.
// Round-12 = round-11 structure (class-sorted rows + fragment-order ebB +
// LDS-staged B + barrier-free 4-panel x 8-stripe sweep) with the ONE change:
// __launch_bounds__(256,2).
//
// HARD RULE (verified rounds 3, 6, 11): (256,4) caps the unified register
// file at 128/wave, the allocator spills the fragment state to scratch, and
// the kernel becomes scratch-BW-bound (FETCH 100-680 MB, 2-5x slower).
// (256,2) gives a 256-reg budget; the real footprint is ~60-90 regs, so
// hardware residency is still 4+ blocks/CU (LDS 32 KB -> 5 blocks/CU cap);
// launch_bounds is an allocator floor, not a residency cap.

#define D 128
#define BM 128   // rows per panel = 4 waves x 32
#define ROWG 4   // panels per block
#define SPLIT 64 // column slices
#define NPART SPLIT
#define NCLS 512
#define MARGIN 0.1f
#define NEG_FLOOR 0.6f
#define NINF -1e30f

typedef short bf16x8 __attribute__((ext_vector_type(8)));
typedef float f32x4 __attribute__((ext_vector_type(4)));

__device__ __forceinline__ unsigned short f2bf(float f) {
  unsigned u = __float_as_uint(f);
  u += 0x7FFFu + ((u >> 16) & 1u);
  return (unsigned short)(u >> 16);
}

// ---- S1: per-chunk class histogram (64 chunks x 128 rows) ----
__global__ void k_hist(const int* __restrict__ tgt, int* __restrict__ H) {
  __shared__ int h[NCLS];
  for (int i = threadIdx.x; i < NCLS; i += 128) h[i] = 0;
  __syncthreads();
  atomicAdd(&h[tgt[blockIdx.x * 128 + threadIdx.x]], 1);
  __syncthreads();
  for (int i = threadIdx.x; i < NCLS; i += 128)
    H[blockIdx.x * NCLS + i] = h[i];
}

// ---- S2: one-block scan -> per-chunk per-class scatter bases ----
__global__ void k_scan(const int* __restrict__ H, int* __restrict__ CB) {
  __shared__ int wsum[8];
  const int c = threadIdx.x;  // class, 512 threads
  int t = 0;
#pragma unroll 8
  for (int k = 0; k < 64; ++k) t += H[k * NCLS + c];
  const int lane = c & 63, w = c >> 6;
  int v = t;
#pragma unroll
  for (int off = 1; off < 64; off <<= 1) {
    int u = __shfl_up(v, off, 64);
    if (lane >= off) v += u;
  }
  if (lane == 63) wsum[w] = v;
  __syncthreads();
  if (c < 8) {
    int x = wsum[c];
#pragma unroll
    for (int off = 1; off < 8; off <<= 1) {
      int u = __shfl_up(x, off, 64);
      if (lane >= off) x += u;
    }
    wsum[c] = x;
  }
  __syncthreads();
  int base = v + ((w > 0) ? wsum[w - 1] : 0) - t;  // exclusive prefix
  int run = base;
#pragma unroll 8
  for (int k = 0; k < 64; ++k) {
    CB[k * NCLS + c] = run;
    run += H[k * NCLS + c];
  }
}

// ---- S3: stable scatter (thread = class, block = chunk) ----
__global__ void k_scatter(const int* __restrict__ tgt,
                          const int* __restrict__ CB, int* __restrict__ perm) {
  const int c = threadIdx.x;  // 512 threads
  int pos = CB[blockIdx.x * NCLS + c];
  const int base = blockIdx.x * 128;
  for (int j = 0; j < 128; ++j) {
    int cls = tgt[base + j];
    if (cls == c) perm[pos++] = base + j;
  }
}

// ---- K1: gather-normalize rows into fragment-order bf16 ----
// ebB chunk (16B) at [(stripe*4+ks)*64+lane] holds sorted row
// stripe*16+(lane&15), elements [(ks*4+(lane>>4))*8 .. +8).
__global__ void k_normB(const float* __restrict__ emb,
                        const int* __restrict__ tgt,
                        const int* __restrict__ perm, uint4* __restrict__ ebB,
                        int* __restrict__ tgtS, int n) {
  const int s = blockIdx.x;         // 16-row (sorted) stripe
  const int rl = threadIdx.x >> 4;  // row within stripe
  const int c = threadIdx.x & 15;   // 16B chunk within row
  const int p = s * 16 + rl;        // sorted row
  const int orig = perm[p];
  const float* q = emb + (size_t)orig * D + c * 8;
  float4 v0 = *(const float4*)q;
  float4 v1 = *(const float4*)(q + 4);
  float ss = v0.x * v0.x + v0.y * v0.y + v0.z * v0.z + v0.w * v0.w +
             v1.x * v1.x + v1.y * v1.y + v1.z * v1.z + v1.w * v1.w;
#pragma unroll
  for (int off = 1; off < 16; off <<= 1) ss += __shfl_xor(ss, off, 64);
  float inv = 1.0f / fmaxf(sqrtf(ss), 1e-12f);
  uint4 wv;
  wv.x = (unsigned)f2bf(v0.x * inv) | ((unsigned)f2bf(v0.y * inv) << 16);
  wv.y = (unsigned)f2bf(v0.z * inv) | ((unsigned)f2bf(v0.w * inv) << 16);
  wv.z = (unsigned)f2bf(v1.x * inv) | ((unsigned)f2bf(v1.y * inv) << 16);
  wv.w = (unsigned)f2bf(v1.z * inv) | ((unsigned)f2bf(v1.w * inv) << 16);
  const int ks = c >> 2, g = c & 3;
  ebB[((s * 4 + ks) * 64) + (g * 16 + rl)] = wv;
  if (c == 0) tgtS[p] = tgt[orig];
}

// ---- K2/K4: LDS-B panel-loop GEMM pass, sorted-class epilogue ----
template <int PASS>
__global__ __launch_bounds__(256, 2) void k_pass5(
    const bf16x8* __restrict__ ebB, const int* __restrict__ tgtS,
    float* __restrict__ mneg_p, float* __restrict__ mpos_p,
    const float* __restrict__ thrNv, const float* __restrict__ thrPv,
    float* __restrict__ loss_p, int n) {
  __shared__ char Bs[32768];  // 8 column stripes x 4 KB, fragment order

  const int lane = threadIdx.x & 63;
  const int w = threadIdx.x >> 6;
  const int l15 = lane & 15, g = lane >> 4;

  const int nStr = (n / SPLIT) / 16;  // 8 stripes per block
  const int cs0 = blockIdx.y * nStr;
  const int pidx = blockIdx.y;
  const int m0 = blockIdx.x * (BM * ROWG);

  // Stage this block's B slice: contiguous 32 KB, linear copy.
  {
    const char* src = (const char*)ebB + (size_t)cs0 * 4096;
#pragma unroll
    for (int i = 0; i < 8; ++i) {
      __builtin_amdgcn_global_load_lds(
          (const __attribute__((address_space(1))) void*)(src + i * 4096 +
                                                          threadIdx.x * 16),
          (__attribute__((address_space(3))) void*)(Bs + i * 4096 +
                                                    threadIdx.x * 16),
          16, 0, 0);
    }
  }
  // Stripe class ranges (wave-uniform scalars).
  int slo[8], shi[8];
#pragma unroll
  for (int si = 0; si < 8; ++si) {
    slo[si] = tgtS[(cs0 + si) * 16];
    shi[si] = tgtS[(cs0 + si) * 16 + 15];
  }
  __syncthreads();  // B resident; no barriers after this point.

#pragma unroll 1
  for (int p = 0; p < ROWG; ++p) {
    const int rbase = m0 + p * BM + w * 32;  // wave's 32-row panel
    const int sA = rbase >> 4;
    const int clo = tgtS[rbase], chi = tgtS[rbase + 31];

    bf16x8 a[2][4];
#pragma unroll
    for (int mt = 0; mt < 2; ++mt)
#pragma unroll
      for (int ks = 0; ks < 4; ++ks)
        a[mt][ks] = ebB[((sA + mt) * 4 + ks) * 64 + lane];

    int tr[2][4];
#pragma unroll
    for (int mt = 0; mt < 2; ++mt) {
      int4 t4 = *(const int4*)(tgtS + rbase + mt * 16 + g * 4);
      tr[mt][0] = t4.x; tr[mt][1] = t4.y; tr[mt][2] = t4.z; tr[mt][3] = t4.w;
    }

    float accN[2][4], accP[2][4], lossA[2][4];
    float thrPmin = 0.f;
#pragma unroll
    for (int mt = 0; mt < 2; ++mt) {
      if (PASS == 0) {
#pragma unroll
        for (int r = 0; r < 4; ++r) {
          accN[mt][r] = NINF;
          accP[mt][r] = NINF;
        }
      } else {
        f32x4 vN = *(const f32x4*)(thrNv + rbase + mt * 16 + g * 4);
        f32x4 vP = *(const f32x4*)(thrPv + rbase + mt * 16 + g * 4);
#pragma unroll
        for (int r = 0; r < 4; ++r) {
          accN[mt][r] = vN[r];
          accP[mt][r] = vP[r];
          lossA[mt][r] = 0.0f;
        }
      }
    }
    if (PASS == 1) {  // wave-min of thr_neg (>= 0.5 via the 0.6 floor)
      float m = accP[0][0];
#pragma unroll
      for (int mt = 0; mt < 2; ++mt)
#pragma unroll
        for (int r = 0; r < 4; ++r) m = fminf(m, accP[mt][r]);
#pragma unroll
      for (int off = 1; off < 64; off <<= 1)
        m = fminf(m, __shfl_xor(m, off, 64));
      thrPmin = m;
    }

#pragma unroll
    for (int si = 0; si < 8; ++si) {
      bf16x8 b[4];
#pragma unroll
      for (int ks = 0; ks < 4; ++ks)
        b[ks] = *(const bf16x8*)(Bs + si * 4096 + ks * 1024 + lane * 16);
      const int cs = cs0 + si;
      const bool dirty = (clo <= shi[si]) && (slo[si] <= chi);

      f32x4 acc[2];
#pragma unroll
      for (int mt = 0; mt < 2; ++mt) acc[mt] = (f32x4){0.f, 0.f, 0.f, 0.f};
#pragma unroll
      for (int ks = 0; ks < 4; ++ks)
#pragma unroll
        for (int mt = 0; mt < 2; ++mt)
          acc[mt] = __builtin_amdgcn_mfma_f32_16x16x32_bf16(a[mt][ks], b[ks],
                                                            acc[mt], 0, 0, 0);
      if (!dirty) {  // pure negatives
        if (PASS == 0) {
#pragma unroll
          for (int mt = 0; mt < 2; ++mt)
#pragma unroll
            for (int r = 0; r < 4; ++r)
              accN[mt][r] = fmaxf(accN[mt][r], acc[mt][r]);
        } else {
#pragma unroll
          for (int mt = 0; mt < 2; ++mt) {
            float mx = fmaxf(fmaxf(acc[mt][0], acc[mt][1]),
                             fmaxf(acc[mt][2], acc[mt][3]));
            if (__any(mx > thrPmin)) {  // rare
#pragma unroll
              for (int r = 0; r < 4; ++r) {
                float s = acc[mt][r];
                lossA[mt][r] += (s > accP[mt][r]) ? s : 0.f;
              }
            }
          }
        }
      } else {  // class-range overlap: full verified path
        const int tc = tgtS[cs * 16 + l15];
#pragma unroll
        for (int mt = 0; mt < 2; ++mt) {
          const bool diagT = (rbase + mt * 16 == cs * 16);
#pragma unroll
          for (int r = 0; r < 4; ++r) {
            float s = acc[mt][r];
            bool same = (tr[mt][r] == tc);
            bool posOk = same && !(diagT && ((g * 4 + r) == l15));
            if (PASS == 0) {
              accN[mt][r] = fmaxf(accN[mt][r], same ? NINF : s);
              accP[mt][r] = fmaxf(accP[mt][r], posOk ? s : NINF);
            } else {
              bool cpos = posOk && (s < accN[mt][r]);
              bool cneg = !same && (s > accP[mt][r]);
              lossA[mt][r] += cpos ? (1.0f - s) : (cneg ? s : 0.f);
            }
          }
        }
      }
    }

    // Per-panel reduce over the 16 l15-lanes; lane l15==0 writes partials.
#pragma unroll
    for (int mt = 0; mt < 2; ++mt) {
#pragma unroll
      for (int r = 0; r < 4; ++r) {
        int row = rbase + mt * 16 + g * 4 + r;
        if (PASS == 0) {
          float vn = accN[mt][r], vp = accP[mt][r];
#pragma unroll
          for (int off = 1; off < 16; off <<= 1) {
            vn = fmaxf(vn, __shfl_xor(vn, off, 64));
            vp = fmaxf(vp, __shfl_xor(vp, off, 64));
          }
          if (l15 == 0) {
            mneg_p[(size_t)pidx * n + row] = vn;
            mpos_p[(size_t)pidx * n + row] = vp;
          }
        } else {
          float vl = lossA[mt][r];
#pragma unroll
          for (int off = 1; off < 16; off <<= 1)
            vl += __shfl_xor(vl, off, 64);
          if (l15 == 0) loss_p[(size_t)pidx * n + row] = vl;
        }
      }
    }
  }
}

// ---- K3: combine partial maxima -> per-row thresholds + has_pos ----
__global__ void k_combine(const float* __restrict__ mneg_p,
                          const float* __restrict__ mpos_p,
                          float* __restrict__ thrNv, float* __restrict__ thrPv,
                          float* __restrict__ hasp, int n) {
  int i = blockIdx.x * blockDim.x + threadIdx.x;
  if (i >= n) return;
  float vn = NINF, vp = NINF;
#pragma unroll
  for (int s = 0; s < NPART; ++s) {
    vn = fmaxf(vn, mneg_p[(size_t)s * n + i]);
    vp = fmaxf(vp, mpos_p[(size_t)s * n + i]);
  }
  thrNv[i] = vn + MARGIN;                    // thr_pos
  thrPv[i] = fmaxf(NEG_FLOOR, vp) - MARGIN;  // thr_neg (>= 0.5)
  hasp[i] = (vp > -1e29f) ? 1.f : 0.f;
}

// ---- K5a/K5b: deterministic final reduction ----
__global__ void k_final1(const float* __restrict__ loss_p,
                         const float* __restrict__ hasp,
                         float* __restrict__ bpart, int n) {
  __shared__ float red[256];
  int i = blockIdx.x * 256 + threadIdx.x;
  float acc = 0.f;
#pragma unroll
  for (int sp = 0; sp < NPART; ++sp) acc += loss_p[(size_t)sp * n + i];
  acc *= hasp[i];
  red[threadIdx.x] = acc;
  __syncthreads();
  for (int off = 128; off > 0; off >>= 1) {
    if ((int)threadIdx.x < off) red[threadIdx.x] += red[threadIdx.x + off];
    __syncthreads();
  }
  if (threadIdx.x == 0) bpart[blockIdx.x] = red[0];
}

__global__ void k_final2(const float* __restrict__ bpart,
                         float* __restrict__ out, int n, int nb) {
  int lane = threadIdx.x & 63;
  float v = (lane < nb) ? bpart[lane] : 0.f;
#pragma unroll
  for (int off = 1; off < 64; off <<= 1) v += __shfl_xor(v, off, 64);
  if (lane == 0) out[0] = v / (float)n;
}

extern "C" void kernel_launch(void* const* d_in, const int* in_sizes, int n_in,
                              void* d_out, int out_size, void* d_ws,
                              size_t ws_size, hipStream_t stream) {
  const float* emb = (const float*)d_in[0];
  const int* tgt = (const int*)d_in[1];
  float* out = (float*)d_out;
  const int n = in_sizes[1];  // 8192

  char* ws = (char*)d_ws;
  uint4* ebB = (uint4*)ws;  // fragment-ordered bf16, 2 MB
  size_t off = (size_t)n * D * sizeof(unsigned short);
  float* mneg_p = (float*)(ws + off);          // [NPART][n]
  float* mpos_p = mneg_p + (size_t)NPART * n;  // [NPART][n]
  float* loss_p = mpos_p + (size_t)NPART * n;  // [NPART][n]
  float* thrNv = loss_p + (size_t)NPART * n;   // [n]
  float* thrPv = thrNv + n;                    // [n]
  float* hasp = thrPv + n;                     // [n]
  float* bpart = hasp + n;                     // [32]
  int* H = (int*)(bpart + 64);                 // [64][512]
  int* CB = H + 64 * NCLS;                     // [64][512]
  int* perm = CB + 64 * NCLS;                  // [n]
  int* tgtS = perm + n;                        // [n]

  k_hist<<<n / 128, 128, 0, stream>>>(tgt, H);
  k_scan<<<1, NCLS, 0, stream>>>(H, CB);
  k_scatter<<<n / 128, NCLS, 0, stream>>>(tgt, CB, perm);
  k_normB<<<n / 16, 256, 0, stream>>>(emb, tgt, perm, ebB, tgtS, n);

  dim3 grid(n / (BM * ROWG), SPLIT);
  k_pass5<0><<<grid, 256, 0, stream>>>((const bf16x8*)ebB, tgtS, mneg_p,
                                       mpos_p, thrNv, thrPv, loss_p, n);
  k_combine<<<(n + 255) / 256, 256, 0, stream>>>(mneg_p, mpos_p, thrNv, thrPv,
                                                 hasp, n);
  k_pass5<1><<<grid, 256, 0, stream>>>((const bf16x8*)ebB, tgtS, mneg_p,
                                       mpos_p, thrNv, thrPv, loss_p, n);
  k_final1<<<n / 256, 256, 0, stream>>>(loss_p, hasp, bpart, n);
  k_final2<<<1, 64, 0, stream>>>(bpart, out, n, n / 256);
}